// Round 3
// baseline (124.443 us; speedup 1.0000x reference)
//
#include <hip/hip_runtime.h>

#define NN    2048
#define CC    64
#define TT    64
#define GRID  2048
#define ITERS 16            // 16*2048 rows / GRID
#define NROWS (16 * 2048)

__global__ __launch_bounds__(256, 4) void cope_kernel(
    const float* __restrict__ q,
    const float* __restrict__ qk,
    const float* __restrict__ pos_emb,
    float* __restrict__ out)
{
    const int tid  = threadIdx.x;   // [0,256)
    const int lane = tid & 63;
    const int wv   = tid >> 6;

    __shared__ float pe[CC * TT];        // 16 KB, bank = (c*64+lane)%32 = lane%32 -> conflict-free
    __shared__ float wave_tot[2][4];     // parity double-buffered (1 barrier/row, no WAR)

    // ---- stage pos_emb once per block ----
    {
        const float4* src = (const float4*)pos_emb;
        float4* dst = (float4*)pe;
#pragma unroll
        for (int i = 0; i < (CC * TT / 4) / 256; ++i)
            dst[tid + i * 256] = src[tid + i * 256];
    }

    int row = blockIdx.x;
    // ---- prefetch first row's qk into registers ----
    const float4* qkp = (const float4*)(qk + (size_t)row * NN);
    float4 a0 = qkp[2 * tid];
    float4 a1 = qkp[2 * tid + 1];

    __syncthreads();   // pe ready

    for (int it = 0; it < ITERS; ++it) {
        // ---- prefetch NEXT row: stays in flight across this row's barrier ----
        float4 b0 = a0, b1 = a1;
        if (it + 1 < ITERS) {
            const float4* np = (const float4*)(qk + (size_t)(row + GRID) * NN);
            b0 = np[2 * tid];
            b1 = np[2 * tid + 1];
        }

        // ---- E[lane], computed redundantly per wave (no cross-wave reduce) ----
        float e;
        {
            const float* qr = q + (size_t)row * CC;   // block-uniform -> scalar loads
            float acc0 = 0.0f, acc1 = 0.0f;
#pragma unroll 8
            for (int c = 0; c < CC; c += 2) {
                acc0 = fmaf(qr[c],     pe[c * TT + lane],       acc0);
                acc1 = fmaf(qr[c + 1], pe[(c + 1) * TT + lane], acc1);
            }
            e = acc0 + acc1;   // lane t holds E[t]
        }

        // ---- sigmoid of my 8 elements ----
        float g[8];
        g[0] = a0.x; g[1] = a0.y; g[2] = a0.z; g[3] = a0.w;
        g[4] = a1.x; g[5] = a1.y; g[6] = a1.z; g[7] = a1.w;
#pragma unroll
        for (int k = 0; k < 8; ++k)
            g[k] = __builtin_amdgcn_rcpf(1.0f + __expf(-g[k]));

        float s = 0.0f;
#pragma unroll
        for (int k = 0; k < 8; ++k) s += g[k];

        // ---- wave-level inclusive suffix scan ----
        float inc = s;
#pragma unroll
        for (int o = 1; o < 64; o <<= 1) {
            float t = __shfl_down(inc, o, 64);
            if (lane + o < 64) inc += t;
        }
        const float X = inc - s;                     // exclusive suffix within wave
        if (lane == 0) wave_tot[it & 1][wv] = inc;   // wave total
        __syncthreads();                             // the ONLY barrier per row

        float W = 0.0f;
#pragma unroll
        for (int w2 = 0; w2 < 4; ++w2)
            if (w2 > wv) W += wave_tot[it & 1][w2];
        const float base = X + W;

        // ---- local suffix, clamp, shfl-gather interp ----
        float o8[8];
        float run = 0.0f;
#pragma unroll
        for (int k = 7; k >= 0; --k) {
            run += g[k];
            float P  = fminf(run + base, 63.0f);
            float fl = floorf(P);
            float w_ = P - fl;
            int   i0 = (int)fl;
            int   i1 = min(i0 + 1, 63);              // == ceil when fractional; w_=0 when integral
            float ef = __shfl(e, i0, 64);
            float ec = __shfl(e, i1, 64);
            o8[k] = fmaf(w_, ec - ef, ef);
        }

        float4* op = (float4*)(out + (size_t)row * NN);
        op[2 * tid]     = make_float4(o8[0], o8[1], o8[2], o8[3]);
        op[2 * tid + 1] = make_float4(o8[4], o8[5], o8[6], o8[7]);

        a0 = b0; a1 = b1;
        row += GRID;
    }
}

extern "C" void kernel_launch(void* const* d_in, const int* in_sizes, int n_in,
                              void* d_out, int out_size, void* d_ws, size_t ws_size,
                              hipStream_t stream) {
    const float* q       = (const float*)d_in[0];
    const float* qk      = (const float*)d_in[1];
    const float* pos_emb = (const float*)d_in[2];
    float* out = (float*)d_out;

    dim3 grid(GRID);
    dim3 block(256);
    cope_kernel<<<grid, block, 0, stream>>>(q, qk, pos_emb, out);
}